// Round 13
// baseline (1448.869 us; speedup 1.0000x reference)
//
#include <hip/hip_runtime.h>
#include <math.h>

// Problem constants (match reference)
#define N_PIX   262144
#define G_NUM   4096
#define K_FREQ  4
#define GSTRIDE 32      // floats per packed gaussian record (128 B)
#define BLOCK   256
#define GSPLIT  32      // 128-gaussian work items: 8 items/wave halves drain tail
#define NBIN1   64      // spatial bins per axis (64x64 = 4096 bins)
#define NBINS   (NBIN1*NBIN1)
#define PPG     128                // pixels per group (2 per lane)
#define NGRP    (N_PIX / PPG)      // 2048 groups
#define NITEMS  (NGRP * GSPLIT)    // 65536 work items
#define NW      (G_NUM / GSPLIT / 64)  // 2 mask words per item
#define NPOOL   8                  // sharded ticket counters
#define NPP     (NITEMS / NPOOL)   // 8192 items per pool
#define GRID_PERS 2048             // 8 blocks/CU x 256 CU = exactly-capacity
// R11: per-gaussian adaptive cull threshold. Keep gaussian g for a group iff
// min_ga(bbox) < cut_g, where cut_g = EPS_LOG + log2(B_g) and
// B_g = (sum|cx|)(sum|cy|)(max|color|). Dropped terms then satisfy
// |contribution| <= 2^-ga * B_g < 2^-EPS_LOG per channel.
#define EPS_LOG 17.0f   // per-term contribution bound 2^-17 ~ 7.6e-6
#define CUT_MAX 12.0f   // never keep less than the old GA_CUT=12 error level
#define CUT_MIN 5.0f

#if __has_builtin(__builtin_amdgcn_exp2f)
#define EXP2F(x) __builtin_amdgcn_exp2f(x)
#else
#define EXP2F(x) exp2f(x)
#endif

// Packed-FP32 pair: half0 = pixel0, half1 = pixel1. <2 x float> arithmetic
// selects v_pk_{mul,add,fma}_f32 on gfx90a+ (gfx950 has HasPackedFP32Ops):
// one instruction = 2 FP32 ops/lane, halving the full-rate VALU stream.
typedef __attribute__((ext_vector_type(2))) float f32x2;

__device__ __forceinline__ f32x2 bc(float s) { return (f32x2){s, s}; }

// cos(2*pi*v) per half: v_fract range-reduce + v_cos (revolutions).
// No packed transcendentals exist; these stay per-half scalar ops.
__device__ __forceinline__ f32x2 cospk(f32x2 v) {
    f32x2 r;
    r.x = __builtin_amdgcn_cosf(__builtin_amdgcn_fractf(v.x));
    r.y = __builtin_amdgcn_cosf(__builtin_amdgcn_fractf(v.y));
    return r;
}

// Pack per-gaussian params into a 32-float record:
// [0..3]  px, py, cos(rot), sin(rot)
// [4..7]  isx*S, isy*S, color0, color1      (S = sqrt(0.5*log2(e)))
// [8..11] color2, qxn, qyn, cut_g
// [12..15] fx[0..3]  [16..19] cx[0..3]  [20..23] fy[0..3]  [24..27] cy[0..3]
__global__ void prep_kernel(const float* __restrict__ colors,
                            const float* __restrict__ pos,
                            const float* __restrict__ scales,
                            const float* __restrict__ rots,
                            const float* __restrict__ coeffs,
                            const int*   __restrict__ idx,
                            float* __restrict__ gp)
{
    int g = blockIdx.x * blockDim.x + threadIdx.x;
    if (g >= G_NUM) return;
    float sr, cr;
    sincosf(rots[g], &sr, &cr);
    const float SC = 0.84932180028801904f;   // sqrt(0.5 * log2(e))
    float isx = expf(scales[2*g + 0]) * SC;
    float isy = expf(scales[2*g + 1]) * SC;
    float gx = pos[2*g], gy = pos[2*g + 1];
    float c0 = colors[3*g], c1 = colors[3*g + 1], c2 = colors[3*g + 2];
    float* o = gp + (size_t)g * GSTRIDE;
    o[0] = gx;  o[1] = gy;  o[2] = cr;  o[3] = sr;
    o[4] = isx; o[5] = isy;
    o[6] = c0;  o[7] = c1;
    o[8] = c2;
    o[9]  = -(gx*cr + gy*sr);   // qxn
    o[10] =  (gx*sr - gy*cr);   // qyn
    const float FS = 1024.0f / 1024.0f;   // MAXF / NF
    float sax = 0.f, say = 0.f;
#pragma unroll
    for (int k = 0; k < K_FREQ; ++k) {
        float cx = coeffs[g*2*K_FREQ + 2*k + 0];
        float cy = coeffs[g*2*K_FREQ + 2*k + 1];
        o[12 + k] = (float)idx[g*2*K_FREQ + 2*k + 0] * FS;
        o[16 + k] = cx;
        o[20 + k] = (float)idx[g*2*K_FREQ + 2*k + 1] * FS;
        o[24 + k] = cy;
        sax += fabsf(cx);
        say += fabsf(cy);
    }
    // per-gaussian adaptive cut: contribution bound B_g = sax*say*max|color|
    float mc = fmaxf(fabsf(c0), fmaxf(fabsf(c1), fabsf(c2)));
    float B  = sax * say * mc;
    float cut = EPS_LOG + log2f(B);          // log2f(0) = -inf -> clamped
    cut = fminf(CUT_MAX, fmaxf(CUT_MIN, cut));
    o[11] = cut;
    o[28] = 0.f; o[29] = 0.f; o[30] = 0.f; o[31] = 0.f;
}

__device__ __forceinline__ int bin_of(float2 P) {
    int bx = (int)(P.x * (float)NBIN1); bx = bx > NBIN1-1 ? NBIN1-1 : bx;
    int by = (int)(P.y * (float)NBIN1); by = by > NBIN1-1 ? NBIN1-1 : by;
    return by * NBIN1 + bx;
}

// --- counting sort of pixels into 64x64 spatial bins (3 tiny kernels) ---
__global__ void hist_kernel(const float2* __restrict__ x, int* __restrict__ hist)
{
    int i = blockIdx.x * blockDim.x + threadIdx.x;
    float2 P = x[i];
    atomicAdd(&hist[bin_of(P)], 1);
}

// Single-block Hillis-Steele inclusive scan over 4096 bins -> exclusive starts.
__global__ __launch_bounds__(1024) void scan_kernel(const int* __restrict__ hist,
                                                    int* __restrict__ start)
{
    __shared__ int s[NBINS];
    const int t = threadIdx.x;
    for (int k = t; k < NBINS; k += 1024) s[k] = hist[k];
    __syncthreads();
    for (int off = 1; off < NBINS; off <<= 1) {
        int v[4];
#pragma unroll
        for (int k = 0; k < 4; ++k) {
            int i = t + 1024*k;
            v[k] = (i >= off) ? s[i - off] : 0;
        }
        __syncthreads();
#pragma unroll
        for (int k = 0; k < 4; ++k) s[t + 1024*k] += v[k];
        __syncthreads();
    }
    for (int k = t; k < NBINS; k += 1024) start[k] = s[k] - hist[k];
}

__global__ void scatter_kernel(const float2* __restrict__ x,
                               const int* __restrict__ start,
                               int* __restrict__ cursor,
                               int* __restrict__ sidx,
                               float2* __restrict__ sx)
{
    int i = blockIdx.x * blockDim.x + threadIdx.x;
    float2 P = x[i];
    int b = bin_of(P);
    int pos = start[b] + atomicAdd(&cursor[b], 1);
    sidx[pos] = i;
    sx[pos]   = P;
}

// Per 128-pixel sorted group: conservative survivor bitmask over all 4096
// gaussians. Include gaussian iff min over the group's bbox of ga < cut_g
// (per-gaussian adaptive threshold from the record). bbox-min is a lower
// bound on any pixel's ga, so exclusion implies per-pixel contribution
// < 2^-EPS_LOG per channel.
__global__ __launch_bounds__(BLOCK) void build_kernel(
    const float2* __restrict__ sx,
    const float*  __restrict__ gp,
    unsigned long long* __restrict__ wmask)
{
    const int lane = threadIdx.x & 63;
    const int grp  = blockIdx.x * (BLOCK/64) + (threadIdx.x >> 6);
    float2 Pa = sx[grp*PPG + lane];
    float2 Pb = sx[grp*PPG + 64 + lane];

    float xmn = fminf(Pa.x, Pb.x), xmx = fmaxf(Pa.x, Pb.x);
    float ymn = fminf(Pa.y, Pb.y), ymx = fmaxf(Pa.y, Pb.y);
    for (int m = 32; m; m >>= 1) {
        xmn = fminf(xmn, __shfl_xor(xmn, m));
        xmx = fmaxf(xmx, __shfl_xor(xmx, m));
        ymn = fminf(ymn, __shfl_xor(ymn, m));
        ymx = fmaxf(ymx, __shfl_xor(ymx, m));
    }
    const float cxp = 0.5f*(xmn + xmx), hx = 0.5f*(xmx - xmn);
    const float cyp = 0.5f*(ymn + ymx), hy = 0.5f*(ymx - ymn);

    const float4* q4 = (const float4*)gp;
    for (int w = 0; w < G_NUM/64; ++w) {
        const int gid = w*64 + lane;
        const float4* q = q4 + (size_t)gid * (GSTRIDE/4);
        const float4 A  = q[0];   // px, py, cr, sr
        const float4 Bv = q[1];   // isx', isy', c0, c1
        const float4 C2 = q[2];   // c2, qxn, qyn, cut_g
        float acr = fabsf(A.z), asr = fabsf(A.w);
        float txc = fmaf(cxp, A.z, fmaf(cyp,  A.w, C2.y));
        float tyc = fmaf(cyp, A.z, fmaf(cxp, -A.w, C2.z));
        float rtx = fmaf(hx, acr, hy * asr);
        float rty = fmaf(hx, asr, hy * acr);
        float mtx = fmaxf(0.f, fabsf(txc) - rtx) * Bv.x;
        float mty = fmaxf(0.f, fabsf(tyc) - rty) * Bv.y;
        float gmin = fmaf(mty, mty, mtx * mtx);
        unsigned long long m = __ballot(gmin < C2.w);
        if (lane == 0) wmask[(size_t)grp * (G_NUM/64) + w] = m;
    }
}

// Walk over 2 preloaded SGPR mask words; returns -1 when item exhausted.
__device__ __forceinline__ int walk_next2(
    int& wi, unsigned long long& word, unsigned long long m1, int gbase)
{
    for (;;) {
        if (word) {
            int b = (int)__builtin_ctzll(word);
            word &= word - 1;
            return gbase + wi * 64 + b;
        }
        if (++wi >= NW) return -1;
        word = m1;
    }
}

// Persistent waves + sharded ticket pools (R5-R7 lessons: 8 pool counters on
// 512B lines; pool forced uniform via readfirstlane else the s_load pipeline
// demotes to VGPR; pop at top / consume at bottom). R9: 2 pixels/lane
// amortizes per-record overhead. R10: packed f32x2 body (v_pk_fma_f32).
// R11: per-gaussian adaptive cut (prep/build only). R13: GSPLIT 16->32 --
// R12 counters showed 24% idle with only 4 items/wave: one item = 1/4 of a
// wave's whole runtime, so last-item spread (duration CV x ~200us) WAS the
// idle. 8 items/wave halves the drain tail; item mask is now a single
// s_load_dwordx4 (NW=2). Survivor set is bit-identical (same test, finer
// partition) -> absmax must stay exactly 4.88e-4.
__global__ __launch_bounds__(BLOCK) void render_kernel(
    const float2* __restrict__ sx,
    const int*    __restrict__ sidx,
    const float*  __restrict__ gp,
    const unsigned long long* __restrict__ wmask,
    int* __restrict__ ticket,
    float* __restrict__ out)
{
    const int lane = threadIdx.x & 63;
    const float4* __restrict__ q4 = (const float4*)gp;

    const int pool = __builtin_amdgcn_readfirstlane(
        (blockIdx.x * (BLOCK/64) + (threadIdx.x >> 6)) & (NPOOL - 1));
    int* __restrict__ tk = ticket + pool * 128;   // 512B-spaced counters

    int t0 = 0;
    if (lane == 0) t0 = atomicAdd(tk, 1);
    int t = __builtin_amdgcn_readfirstlane(t0);

    while (t < NPP) {
        // pop next ticket now; result consumed only at the bottom
        int t1 = 0;
        if (lane == 0) t1 = atomicAdd(tk, 1);

        const int item  = t * NPOOL + pool;
        const int grp   = item & (NGRP - 1);
        const int split = item >> 11;            // NGRP = 2048 = 2^11
        const int gbase = split * (G_NUM / GSPLIT);
        const unsigned long long* mw =
            wmask + (size_t)grp * (G_NUM/64) + split * NW;

        // whole item mask in one s_load_dwordx4 (4 SGPRs)
        const ulonglong2 mv = ((const ulonglong2*)mw)[0];

        const float2 P0  = sx[grp*PPG + lane];
        const float2 P1  = sx[grp*PPG + 64 + lane];
        const int   pix0 = sidx[grp*PPG + lane];
        const int   pix1 = sidx[grp*PPG + 64 + lane];

        const f32x2 Px = {P0.x, P1.x};
        const f32x2 Py = {P0.y, P1.y};

        f32x2 ar = {0.f, 0.f}, ag = {0.f, 0.f}, ab = {0.f, 0.f};

        int wi = 0;
        unsigned long long word = mv.x;
        int cur = walk_next2(wi, word, mv.y, gbase);

        if (cur >= 0) {
            const float4* q = q4 + (size_t)cur * (GSTRIDE/4);
            float4 A  = q[0];
            float4 Bv = q[1];
            float4 C2 = q[2];
            float4 FX = q[3];
            float4 CX = q[4];
            float4 FY = q[5];
            float4 CY = q[6];

            for (;;) {
                int nxt = walk_next2(wi, word, mv.y, gbase);
                // prefetch next record (reload current on last iter; harmless)
                const int pidx = (nxt < 0) ? cur : nxt;
                const float4* qn = q4 + (size_t)pidx * (GSTRIDE/4);
                const float4 An  = qn[0];
                const float4 Bn  = qn[1];
                const float4 C2n = qn[2];
                const float4 FXn = qn[3];
                const float4 CXn = qn[4];
                const float4 FYn = qn[5];
                const float4 CYn = qn[6];

                // packed pixel-pair body (contraction -> v_pk_fma_f32)
                f32x2 tx = Px * bc(A.z) + (Py * bc( A.w) + bc(C2.y));
                f32x2 ty = Py * bc(A.z) + (Px * bc(-A.w) + bc(C2.z));
                f32x2 bx = tx * bc(Bv.x);
                f32x2 by = ty * bc(Bv.y);
                f32x2 ga = bx * bx + by * by;
                f32x2 gw;
                gw.x = EXP2F(-ga.x);
                gw.y = EXP2F(-ga.y);

                f32x2 wx =      bc(CX.x) * cospk(tx * bc(FX.x));
                wx = wx + bc(CX.y) * cospk(tx * bc(FX.y));
                wx = wx + bc(CX.z) * cospk(tx * bc(FX.z));
                wx = wx + bc(CX.w) * cospk(tx * bc(FX.w));
                f32x2 wy =      bc(CY.x) * cospk(ty * bc(FY.x));
                wy = wy + bc(CY.y) * cospk(ty * bc(FY.y));
                wy = wy + bc(CY.z) * cospk(ty * bc(FY.z));
                wy = wy + bc(CY.w) * cospk(ty * bc(FY.w));

                f32x2 w = (gw * wx) * wy;
                ar = ar + w * bc(Bv.z);
                ag = ag + w * bc(Bv.w);
                ab = ab + w * bc(C2.x);

                if (nxt < 0) break;
                A = An; Bv = Bn; C2 = C2n; FX = FXn; CX = CXn; FY = FYn; CY = CYn;
                cur = nxt;
            }
        }

        const int o0 = pix0 * 3;
        atomicAdd(&out[o0 + 0], ar.x);
        atomicAdd(&out[o0 + 1], ag.x);
        atomicAdd(&out[o0 + 2], ab.x);
        const int o1 = pix1 * 3;
        atomicAdd(&out[o1 + 0], ar.y);
        atomicAdd(&out[o1 + 1], ag.y);
        atomicAdd(&out[o1 + 2], ab.y);

        // consume the pop issued at the top; waitcnt lands here, hidden
        t = __builtin_amdgcn_readfirstlane(t1);
    }
}

extern "C" void kernel_launch(void* const* d_in, const int* in_sizes, int n_in,
                              void* d_out, int out_size, void* d_ws, size_t ws_size,
                              hipStream_t stream) {
    const float* x      = (const float*)d_in[0];   // [N,2]
    const float* colors = (const float*)d_in[1];   // [G,3]
    const float* pos    = (const float*)d_in[2];   // [G,2]
    const float* scales = (const float*)d_in[3];   // [G,2]
    const float* rots   = (const float*)d_in[4];   // [G,1]
    const float* coeffs = (const float*)d_in[5];   // [G,K,2]
    const int*   idx    = (const int*)d_in[6];     // [G,K,2]
    float* out = (float*)d_out;

    // Workspace layout (needs ~4.7 MB):
    //   [0, 512K)          gp      gaussian records
    //   [512K, +16K)       hist    bin histogram   (memset each launch)
    //   [528K, +16K)       cursor  scatter cursors (memset each launch)
    //   [544K, +4K)        ticket  8 pool counters, 512B apart (memset)
    //   [548K, +16K)       start   exclusive bin starts
    //   [564K, +1M)        sidx    sorted -> original pixel index
    //   [564K+1M, +2M)     sx      sorted pixel coords (float2)
    //   [564K+3M, +1M)     wmask   per-group survivor bitmasks (2048 x 64 u64)
    char* ws = (char*)d_ws;
    float*  gp     = (float*)(ws);
    int*    hist   = (int*)(ws + 524288);
    int*    cursor = (int*)(ws + 524288 + 16384);
    int*    ticket = (int*)(ws + 524288 + 32768);
    int*    start  = (int*)(ws + 524288 + 36864);
    int*    sidx   = (int*)(ws + 524288 + 53248);
    float2* sx     = (float2*)(ws + 524288 + 53248 + 1048576);
    unsigned long long* wmask =
        (unsigned long long*)(ws + 524288 + 53248 + 1048576 + 2097152);

    prep_kernel<<<(G_NUM + 255) / 256, 256, 0, stream>>>(
        colors, pos, scales, rots, coeffs, idx, gp);

    // zero hist + cursor + tickets (adjacent, 36 KB) and the output
    hipMemsetAsync(hist, 0, 36864, stream);
    hipMemsetAsync(out, 0, (size_t)out_size * sizeof(float), stream);

    hist_kernel<<<N_PIX / 256, 256, 0, stream>>>((const float2*)x, hist);
    scan_kernel<<<1, 1024, 0, stream>>>(hist, start);
    scatter_kernel<<<N_PIX / 256, 256, 0, stream>>>((const float2*)x, start,
                                                    cursor, sidx, sx);
    build_kernel<<<NGRP / (BLOCK/64), BLOCK, 0, stream>>>(sx, gp, wmask);

    render_kernel<<<GRID_PERS, BLOCK, 0, stream>>>(sx, sidx, gp, wmask,
                                                   ticket, out);
}

// Round 15
// 835.803 us; speedup vs baseline: 1.7335x; 1.7335x over previous
//
#include <hip/hip_runtime.h>
#include <math.h>

// Problem constants (match reference)
#define N_PIX   262144
#define G_NUM   4096
#define K_FREQ  4
#define GSTRIDE 32      // floats per packed gaussian record (128 B)
#define BLOCK   256
#define GSPLIT  16      // 256-gaussian work items (R13 lesson: 32 doubled the
                        // atomic flush count and hit the ~19G/s atomic ceiling)
#define NBIN1   64      // spatial bins per axis (64x64 = 4096 bins)
#define NBINS   (NBIN1*NBIN1)
#define PPG     128                // pixels per group (2 per lane)
#define NGRP    (N_PIX / PPG)      // 2048 groups
#define NITEMS  (NGRP * GSPLIT)    // 32768 work items
#define NW      (G_NUM / GSPLIT / 64)  // 4 mask words per item
#define NPOOL   8                  // sharded ticket counters
#define NPP     (NITEMS / NPOOL)   // 4096 items per pool
#define GRID_PERS 2048             // 8 blocks/CU x 256 CU = exactly-capacity
// R11: per-gaussian adaptive cull threshold (see prep_kernel).
#define EPS_LOG 17.0f   // per-term contribution bound 2^-17 ~ 7.6e-6
#define CUT_MAX 12.0f
#define CUT_MIN 5.0f

#if __has_builtin(__builtin_amdgcn_exp2f)
#define EXP2F(x) __builtin_amdgcn_exp2f(x)
#else
#define EXP2F(x) exp2f(x)
#endif

// Packed-FP32 pair: half0 = pixel0, half1 = pixel1 -> v_pk_{mul,add,fma}_f32.
typedef __attribute__((ext_vector_type(2))) float f32x2;

__device__ __forceinline__ f32x2 bc(float s) { return (f32x2){s, s}; }

__device__ __forceinline__ f32x2 cospk(f32x2 v) {
    f32x2 r;
    r.x = __builtin_amdgcn_cosf(__builtin_amdgcn_fractf(v.x));
    r.y = __builtin_amdgcn_cosf(__builtin_amdgcn_fractf(v.y));
    return r;
}

// Pack per-gaussian params into a 32-float record:
// [0..3]  px, py, cos(rot), sin(rot)
// [4..7]  isx*S, isy*S, color0, color1      (S = sqrt(0.5*log2(e)))
// [8..11] color2, qxn, qyn, cut_g
// [12..15] fx[0..3]  [16..19] cx[0..3]  [20..23] fy[0..3]  [24..27] cy[0..3]
__global__ void prep_kernel(const float* __restrict__ colors,
                            const float* __restrict__ pos,
                            const float* __restrict__ scales,
                            const float* __restrict__ rots,
                            const float* __restrict__ coeffs,
                            const int*   __restrict__ idx,
                            float* __restrict__ gp)
{
    int g = blockIdx.x * blockDim.x + threadIdx.x;
    if (g >= G_NUM) return;
    float sr, cr;
    sincosf(rots[g], &sr, &cr);
    const float SC = 0.84932180028801904f;   // sqrt(0.5 * log2(e))
    float isx = expf(scales[2*g + 0]) * SC;
    float isy = expf(scales[2*g + 1]) * SC;
    float gx = pos[2*g], gy = pos[2*g + 1];
    float c0 = colors[3*g], c1 = colors[3*g + 1], c2 = colors[3*g + 2];
    float* o = gp + (size_t)g * GSTRIDE;
    o[0] = gx;  o[1] = gy;  o[2] = cr;  o[3] = sr;
    o[4] = isx; o[5] = isy;
    o[6] = c0;  o[7] = c1;
    o[8] = c2;
    o[9]  = -(gx*cr + gy*sr);   // qxn
    o[10] =  (gx*sr - gy*cr);   // qyn
    const float FS = 1024.0f / 1024.0f;   // MAXF / NF
    float sax = 0.f, say = 0.f;
#pragma unroll
    for (int k = 0; k < K_FREQ; ++k) {
        float cx = coeffs[g*2*K_FREQ + 2*k + 0];
        float cy = coeffs[g*2*K_FREQ + 2*k + 1];
        o[12 + k] = (float)idx[g*2*K_FREQ + 2*k + 0] * FS;
        o[16 + k] = cx;
        o[20 + k] = (float)idx[g*2*K_FREQ + 2*k + 1] * FS;
        o[24 + k] = cy;
        sax += fabsf(cx);
        say += fabsf(cy);
    }
    // per-gaussian adaptive cut: contribution bound B_g = sax*say*max|color|
    float mc = fmaxf(fabsf(c0), fmaxf(fabsf(c1), fabsf(c2)));
    float B  = sax * say * mc;
    float cut = EPS_LOG + log2f(B);          // log2f(0) = -inf -> clamped
    cut = fminf(CUT_MAX, fmaxf(CUT_MIN, cut));
    o[11] = cut;
    o[28] = 0.f; o[29] = 0.f; o[30] = 0.f; o[31] = 0.f;
}

__device__ __forceinline__ int bin_of(float2 P) {
    int bx = (int)(P.x * (float)NBIN1); bx = bx > NBIN1-1 ? NBIN1-1 : bx;
    int by = (int)(P.y * (float)NBIN1); by = by > NBIN1-1 ? NBIN1-1 : by;
    return by * NBIN1 + bx;
}

// --- counting sort of pixels into 64x64 spatial bins (3 tiny kernels) ---
__global__ void hist_kernel(const float2* __restrict__ x, int* __restrict__ hist)
{
    int i = blockIdx.x * blockDim.x + threadIdx.x;
    float2 P = x[i];
    atomicAdd(&hist[bin_of(P)], 1);
}

__global__ __launch_bounds__(1024) void scan_kernel(const int* __restrict__ hist,
                                                    int* __restrict__ start)
{
    __shared__ int s[NBINS];
    const int t = threadIdx.x;
    for (int k = t; k < NBINS; k += 1024) s[k] = hist[k];
    __syncthreads();
    for (int off = 1; off < NBINS; off <<= 1) {
        int v[4];
#pragma unroll
        for (int k = 0; k < 4; ++k) {
            int i = t + 1024*k;
            v[k] = (i >= off) ? s[i - off] : 0;
        }
        __syncthreads();
#pragma unroll
        for (int k = 0; k < 4; ++k) s[t + 1024*k] += v[k];
        __syncthreads();
    }
    for (int k = t; k < NBINS; k += 1024) start[k] = s[k] - hist[k];
}

__global__ void scatter_kernel(const float2* __restrict__ x,
                               const int* __restrict__ start,
                               int* __restrict__ cursor,
                               int* __restrict__ sidx,
                               float2* __restrict__ sx)
{
    int i = blockIdx.x * blockDim.x + threadIdx.x;
    float2 P = x[i];
    int b = bin_of(P);
    int pos = start[b] + atomicAdd(&cursor[b], 1);
    sidx[pos] = i;
    sx[pos]   = P;
}

// Per 128-pixel sorted group: conservative survivor bitmask (ga-bbox-min vs
// per-gaussian adaptive cut_g).
__global__ __launch_bounds__(BLOCK) void build_kernel(
    const float2* __restrict__ sx,
    const float*  __restrict__ gp,
    unsigned long long* __restrict__ wmask)
{
    const int lane = threadIdx.x & 63;
    const int grp  = blockIdx.x * (BLOCK/64) + (threadIdx.x >> 6);
    float2 Pa = sx[grp*PPG + lane];
    float2 Pb = sx[grp*PPG + 64 + lane];

    float xmn = fminf(Pa.x, Pb.x), xmx = fmaxf(Pa.x, Pb.x);
    float ymn = fminf(Pa.y, Pb.y), ymx = fmaxf(Pa.y, Pb.y);
    for (int m = 32; m; m >>= 1) {
        xmn = fminf(xmn, __shfl_xor(xmn, m));
        xmx = fmaxf(xmx, __shfl_xor(xmx, m));
        ymn = fminf(ymn, __shfl_xor(ymn, m));
        ymx = fmaxf(ymx, __shfl_xor(ymx, m));
    }
    const float cxp = 0.5f*(xmn + xmx), hx = 0.5f*(xmx - xmn);
    const float cyp = 0.5f*(ymn + ymx), hy = 0.5f*(ymx - ymn);

    const float4* q4 = (const float4*)gp;
    for (int w = 0; w < G_NUM/64; ++w) {
        const int gid = w*64 + lane;
        const float4* q = q4 + (size_t)gid * (GSTRIDE/4);
        const float4 A  = q[0];   // px, py, cr, sr
        const float4 Bv = q[1];   // isx', isy', c0, c1
        const float4 C2 = q[2];   // c2, qxn, qyn, cut_g
        float acr = fabsf(A.z), asr = fabsf(A.w);
        float txc = fmaf(cxp, A.z, fmaf(cyp,  A.w, C2.y));
        float tyc = fmaf(cyp, A.z, fmaf(cxp, -A.w, C2.z));
        float rtx = fmaf(hx, acr, hy * asr);
        float rty = fmaf(hx, asr, hy * acr);
        float mtx = fmaxf(0.f, fabsf(txc) - rtx) * Bv.x;
        float mty = fmaxf(0.f, fabsf(tyc) - rty) * Bv.y;
        float gmin = fmaf(mty, mty, mtx * mtx);
        unsigned long long m = __ballot(gmin < C2.w);
        if (lane == 0) wmask[(size_t)grp * (G_NUM/64) + w] = m;
    }
}

// Walk over 4 preloaded SGPR mask words; returns -1 when item exhausted.
__device__ __forceinline__ int walk_next4(
    int& wi, unsigned long long& word,
    unsigned long long m1, unsigned long long m2, unsigned long long m3,
    int gbase)
{
    for (;;) {
        if (word) {
            int b = (int)__builtin_ctzll(word);
            word &= word - 1;
            return gbase + wi * 64 + b;
        }
        if (++wi >= NW) return -1;
        word = (wi==1) ? m1 : (wi==2) ? m2 : m3;
    }
}

// Persistent waves + sharded ticket pools (R5-R7) + 2px/lane (R9) + packed
// f32x2 body (R10) + adaptive cut (R11). R14/R15: render atomics REMOVED when
// the workspace allows (USE_PARTIAL). R13 counters proved device-scope f32
// atomicAdd to out[] writes through to HBM (31 B/lane-atomic in WRITE_SIZE)
// and serves ~19G lane-atomics/s -- the binding ceiling at GSPLIT>=16.
// Partial path: each item writes its RGB partials to a private 1536 B slot
// with 6 coalesced 256 B wave-stores; reduce_kernel sums the GSPLIT slots.
// ITEM INDEX CONVENTION (R14 bug was a mismatch here): item = split*NGRP+grp,
// i.e. grp = item & (NGRP-1), split = item >> 11. The partial slot for
// (grp, split) lives at partial + item*384 = (split*NGRP + grp)*384.
template<bool USE_PARTIAL>
__global__ __launch_bounds__(BLOCK) void render_kernel(
    const float2* __restrict__ sx,
    const int*    __restrict__ sidx,
    const float*  __restrict__ gp,
    const unsigned long long* __restrict__ wmask,
    int* __restrict__ ticket,
    float* __restrict__ partial,
    float* __restrict__ out)
{
    const int lane = threadIdx.x & 63;
    const float4* __restrict__ q4 = (const float4*)gp;

    const int pool = __builtin_amdgcn_readfirstlane(
        (blockIdx.x * (BLOCK/64) + (threadIdx.x >> 6)) & (NPOOL - 1));
    int* __restrict__ tk = ticket + pool * 128;   // 512B-spaced counters

    int t0 = 0;
    if (lane == 0) t0 = atomicAdd(tk, 1);
    int t = __builtin_amdgcn_readfirstlane(t0);

    while (t < NPP) {
        // pop next ticket now; result consumed only at the bottom
        int t1 = 0;
        if (lane == 0) t1 = atomicAdd(tk, 1);

        const int item  = t * NPOOL + pool;
        const int grp   = item & (NGRP - 1);
        const int split = item >> 11;            // NGRP = 2048 = 2^11
        const int gbase = split * (G_NUM / GSPLIT);
        const unsigned long long* mw =
            wmask + (size_t)grp * (G_NUM/64) + split * NW;

        // whole item mask in one s_load_dwordx8 (8 SGPRs)
        const ulonglong4 mv = ((const ulonglong4*)mw)[0];

        const float2 P0  = sx[grp*PPG + lane];
        const float2 P1  = sx[grp*PPG + 64 + lane];

        const f32x2 Px = {P0.x, P1.x};
        const f32x2 Py = {P0.y, P1.y};

        f32x2 ar = {0.f, 0.f}, ag = {0.f, 0.f}, ab = {0.f, 0.f};

        int wi = 0;
        unsigned long long word = mv.x;
        int cur = walk_next4(wi, word, mv.y, mv.z, mv.w, gbase);

        if (cur >= 0) {
            const float4* q = q4 + (size_t)cur * (GSTRIDE/4);
            float4 A  = q[0];
            float4 Bv = q[1];
            float4 C2 = q[2];
            float4 FX = q[3];
            float4 CX = q[4];
            float4 FY = q[5];
            float4 CY = q[6];

            for (;;) {
                int nxt = walk_next4(wi, word, mv.y, mv.z, mv.w, gbase);
                // prefetch next record (reload current on last iter; harmless)
                const int pidx = (nxt < 0) ? cur : nxt;
                const float4* qn = q4 + (size_t)pidx * (GSTRIDE/4);
                const float4 An  = qn[0];
                const float4 Bn  = qn[1];
                const float4 C2n = qn[2];
                const float4 FXn = qn[3];
                const float4 CXn = qn[4];
                const float4 FYn = qn[5];
                const float4 CYn = qn[6];

                // packed pixel-pair body (contraction -> v_pk_fma_f32)
                f32x2 tx = Px * bc(A.z) + (Py * bc( A.w) + bc(C2.y));
                f32x2 ty = Py * bc(A.z) + (Px * bc(-A.w) + bc(C2.z));
                f32x2 bx = tx * bc(Bv.x);
                f32x2 by = ty * bc(Bv.y);
                f32x2 ga = bx * bx + by * by;
                f32x2 gw;
                gw.x = EXP2F(-ga.x);
                gw.y = EXP2F(-ga.y);

                f32x2 wx =      bc(CX.x) * cospk(tx * bc(FX.x));
                wx = wx + bc(CX.y) * cospk(tx * bc(FX.y));
                wx = wx + bc(CX.z) * cospk(tx * bc(FX.z));
                wx = wx + bc(CX.w) * cospk(tx * bc(FX.w));
                f32x2 wy =      bc(CY.x) * cospk(ty * bc(FY.x));
                wy = wy + bc(CY.y) * cospk(ty * bc(FY.y));
                wy = wy + bc(CY.z) * cospk(ty * bc(FY.z));
                wy = wy + bc(CY.w) * cospk(ty * bc(FY.w));

                f32x2 w = (gw * wx) * wy;
                ar = ar + w * bc(Bv.z);
                ag = ag + w * bc(Bv.w);
                ab = ab + w * bc(C2.x);

                if (nxt < 0) break;
                A = An; Bv = Bn; C2 = C2n; FX = FXn; CX = CXn; FY = FYn; CY = CYn;
                cur = nxt;
            }
        }

        if (USE_PARTIAL) {
            // private slot, 6 coalesced 256B wave-stores; layout [item][3][128]
            float* pb = partial + (size_t)item * 384;
            pb[0*128 +      lane] = ar.x;
            pb[0*128 + 64 + lane] = ar.y;
            pb[1*128 +      lane] = ag.x;
            pb[1*128 + 64 + lane] = ag.y;
            pb[2*128 +      lane] = ab.x;
            pb[2*128 + 64 + lane] = ab.y;
        } else {
            const int pix0 = sidx[grp*PPG + lane];
            const int pix1 = sidx[grp*PPG + 64 + lane];
            const int o0 = pix0 * 3;
            atomicAdd(&out[o0 + 0], ar.x);
            atomicAdd(&out[o0 + 1], ag.x);
            atomicAdd(&out[o0 + 2], ab.x);
            const int o1 = pix1 * 3;
            atomicAdd(&out[o1 + 0], ar.y);
            atomicAdd(&out[o1 + 1], ag.y);
            atomicAdd(&out[o1 + 2], ab.y);
        }

        // consume the pop issued at the top; waitcnt lands here, hidden
        t = __builtin_amdgcn_readfirstlane(t1);
    }
}

// Sum the GSPLIT partial slots for each sorted pixel slot, scatter to out.
// Thread i -> (grp = i>>7, slot = i&127). Slot for (grp, split=s) is at
// partial + (s*NGRP + grp)*384  [matches render's item = split*NGRP + grp;
// R14's bug was assuming grp*GSPLIT + s here]. Reads coalesced over slot.
__global__ __launch_bounds__(BLOCK) void reduce_kernel(
    const float* __restrict__ partial,
    const int*   __restrict__ sidx,
    float* __restrict__ out)
{
    const int i    = blockIdx.x * BLOCK + threadIdx.x;
    const int grp  = i >> 7;
    const int slot = i & 127;
    const float* p = partial + (size_t)grp * 384 + slot;   // split=0 slot
    const size_t SSTRIDE = (size_t)NGRP * 384;             // split stride
    float r = 0.f, g = 0.f, b = 0.f;
#pragma unroll
    for (int s = 0; s < GSPLIT; ++s) {
        r += p[s*SSTRIDE + 0*128];
        g += p[s*SSTRIDE + 1*128];
        b += p[s*SSTRIDE + 2*128];
    }
    const int pix = sidx[i];
    out[pix*3 + 0] = r;
    out[pix*3 + 1] = g;
    out[pix*3 + 2] = b;
}

extern "C" void kernel_launch(void* const* d_in, const int* in_sizes, int n_in,
                              void* d_out, int out_size, void* d_ws, size_t ws_size,
                              hipStream_t stream) {
    const float* x      = (const float*)d_in[0];   // [N,2]
    const float* colors = (const float*)d_in[1];   // [G,3]
    const float* pos    = (const float*)d_in[2];   // [G,2]
    const float* scales = (const float*)d_in[3];   // [G,2]
    const float* rots   = (const float*)d_in[4];   // [G,1]
    const float* coeffs = (const float*)d_in[5];   // [G,K,2]
    const int*   idx    = (const int*)d_in[6];     // [G,K,2]
    float* out = (float*)d_out;

    // Workspace layout:
    //   [0, 512K)          gp      gaussian records
    //   [512K, +16K)       hist    bin histogram   (memset each launch)
    //   [528K, +16K)       cursor  scatter cursors (memset each launch)
    //   [544K, +4K)        ticket  8 pool counters, 512B apart (memset)
    //   [548K, +16K)       start   exclusive bin starts
    //   [564K, +1M)        sidx    sorted -> original pixel index
    //   [564K+1M, +2M)     sx      sorted pixel coords (float2)
    //   [564K+3M, +1M)     wmask   per-group survivor bitmasks (2048 x 64 u64)
    //   [~4.66M, +48M)     partial per-item RGB partials (if ws permits)
    char* ws = (char*)d_ws;
    float*  gp     = (float*)(ws);
    int*    hist   = (int*)(ws + 524288);
    int*    cursor = (int*)(ws + 524288 + 16384);
    int*    ticket = (int*)(ws + 524288 + 32768);
    int*    start  = (int*)(ws + 524288 + 36864);
    int*    sidx   = (int*)(ws + 524288 + 53248);
    float2* sx     = (float2*)(ws + 524288 + 53248 + 1048576);
    unsigned long long* wmask =
        (unsigned long long*)(ws + 524288 + 53248 + 1048576 + 2097152);
    const size_t base_end = 524288 + 53248 + 1048576 + 2097152 + 1048576;
    float* partial = (float*)(ws + base_end);
    const size_t partial_bytes = (size_t)NITEMS * 384 * sizeof(float); // 48 MB
    const bool use_partial = (ws_size >= base_end + partial_bytes);

    prep_kernel<<<(G_NUM + 255) / 256, 256, 0, stream>>>(
        colors, pos, scales, rots, coeffs, idx, gp);

    // zero hist + cursor + tickets (adjacent, 36 KB)
    hipMemsetAsync(hist, 0, 36864, stream);
    if (!use_partial)   // atomic path accumulates into out
        hipMemsetAsync(out, 0, (size_t)out_size * sizeof(float), stream);

    hist_kernel<<<N_PIX / 256, 256, 0, stream>>>((const float2*)x, hist);
    scan_kernel<<<1, 1024, 0, stream>>>(hist, start);
    scatter_kernel<<<N_PIX / 256, 256, 0, stream>>>((const float2*)x, start,
                                                    cursor, sidx, sx);
    build_kernel<<<NGRP / (BLOCK/64), BLOCK, 0, stream>>>(sx, gp, wmask);

    if (use_partial) {
        render_kernel<true><<<GRID_PERS, BLOCK, 0, stream>>>(
            sx, sidx, gp, wmask, ticket, partial, out);
        reduce_kernel<<<N_PIX / BLOCK, BLOCK, 0, stream>>>(partial, sidx, out);
    } else {
        render_kernel<false><<<GRID_PERS, BLOCK, 0, stream>>>(
            sx, sidx, gp, wmask, ticket, partial, out);
    }
}